// Round 12
// baseline (2363.375 us; speedup 1.0000x reference)
//
#include <hip/hip_runtime.h>

#define B 8
#define N 16384
#define C_IN 32
#define P 1024

typedef float v2f __attribute__((ext_vector_type(2)));
typedef unsigned long long ull;

// ---------------------------------------------------------------------------
// R12: two plain kernels, no cross-block synchronization of any kind.
//  1) fps_prep_kernel — byte-for-byte the passing R9 kernel: blocks 0..7 run
//     frozen-R7 FPS (~1810us); blocks 8..519 do transpose+SoA prep, hidden
//     under the FPS shadow.
//  2) fused_kernel — each WAVE owns one (b,p) item end-to-end: ballq (idx in
//     wave-private LDS) -> gather -> conv1+BN+ReLU -> conv2+BN -> max ->
//     store. Wave-synchronous: ZERO barriers after weight staging, no
//     atomics, no spins -> deadlock-impossible. Removes: 2 launches, idx
//     global round-trip, and all per-point __syncthreads of the R9 mlp.
// All arithmetic chains bitwise-identical to the passing R9 kernel.
// ---------------------------------------------------------------------------
#define R8M(OP) OP(0) OP(1) OP(2) OP(3) OP(4) OP(5) OP(6) OP(7)

__device__ __forceinline__ v2f pk_add(v2f a, v2f b) {
  v2f d; asm("v_pk_add_f32 %0, %1, %2" : "=v"(d) : "v"(a), "v"(b)); return d;
}
__device__ __forceinline__ v2f pk_mul(v2f a, v2f b) {
  v2f d; asm("v_pk_mul_f32 %0, %1, %2" : "=v"(d) : "v"(a), "v"(b)); return d;
}
__device__ __forceinline__ float negf(float x) {
  return __int_as_float(__float_as_int(x) ^ 0x80000000);
}
template <int CTRL>
__device__ __forceinline__ float dpp_fmax(float v) {
  float o = __int_as_float(__builtin_amdgcn_update_dpp(
      __float_as_int(v), __float_as_int(v), CTRL, 0xF, 0xF, false));
  return fmaxf(v, o);
}

// ================= kernel 1: FPS + prep (R9 verbatim) =================
__global__ __launch_bounds__(1024)
void fps_prep_kernel(const float* __restrict__ xyz,
                     const float* __restrict__ feats,
                     float* __restrict__ new_xyz,
                     float* __restrict__ ftr,
                     float* __restrict__ sox, float* __restrict__ soy,
                     float* __restrict__ soz)
{
  __shared__ __align__(16) char smem[131088];
  const int t = threadIdx.x;

  if (blockIdx.x >= 8) {
    // ---------------- prep path: transpose + SoA ----------------
    const int pid   = blockIdx.x - 8;          // 0..511
    const int pb    = pid >> 6;                // batch
    const int n0    = (pid & 63) << 8;         // 256-point chunk
    const float* fb = feats + (size_t)pb * (C_IN * N);
    const float* xb = xyz + (size_t)pb * (N * 3);
    float (*tile)[257] = (float(*)[257])smem;

    {
      const int c  = t >> 5;            // 0..31
      const int nn = (t & 31) << 3;     // 0..248
      const float* src = fb + (size_t)c * N + n0 + nn;
      const float4 a0 = *(const float4*)(src);
      const float4 a1 = *(const float4*)(src + 4);
      tile[c][nn + 0] = a0.x; tile[c][nn + 1] = a0.y;
      tile[c][nn + 2] = a0.z; tile[c][nn + 3] = a0.w;
      tile[c][nn + 4] = a1.x; tile[c][nn + 5] = a1.y;
      tile[c][nn + 6] = a1.z; tile[c][nn + 7] = a1.w;
    }
    if (t < 256) {
      const int n = n0 + t;
      const size_t o = (size_t)pb * N + n;
      sox[o] = xb[(size_t)n * 3 + 0];
      soy[o] = xb[(size_t)n * 3 + 1];
      soz[o] = xb[(size_t)n * 3 + 2];
    }
    __syncthreads();
    {
      const int n  = t >> 2;            // 0..255
      const int c0 = (t & 3) << 3;      // 0,8,16,24
      float4 o0, o1;
      o0.x = tile[c0 + 0][n]; o0.y = tile[c0 + 1][n];
      o0.z = tile[c0 + 2][n]; o0.w = tile[c0 + 3][n];
      o1.x = tile[c0 + 4][n]; o1.y = tile[c0 + 5][n];
      o1.z = tile[c0 + 6][n]; o1.w = tile[c0 + 7][n];
      float4* dst = (float4*)(ftr + ((size_t)pb * N + n0 + n) * 32 + c0);
      dst[0] = o0;
      dst[1] = o1;
    }
    return;
  }

  // ---------------- FPS path (frozen R7 logic) ----------------
  float* sx = (float*)smem;
  float* sy = sx + N;
  ull*  slot = (ull*)(smem + 2 * N * sizeof(float));

  const int b = blockIdx.x;
  const float* xb = xyz + (size_t)b * (N * 3);

  if (t == 0) { slot[0] = ~0ull; slot[1] = ~0ull; }

#define FPS_DECL(j) v2f pzp##j, dmp##j; dmp##j.x = 1e10f; dmp##j.y = 1e10f;
  R8M(FPS_DECL)
#define FPS_LOADP(j) {                                                         \
    const int n0 = (t << 2) + ((j >> 1) << 12) + ((j & 1) << 1);               \
    const float2 ld0 = *(const float2*)&xb[(size_t)n0 * 3 + 0];                \
    const float2 ld1 = *(const float2*)&xb[(size_t)n0 * 3 + 2];                \
    const float2 ld2 = *(const float2*)&xb[(size_t)n0 * 3 + 4];                \
    sx[n0]     = ld0.x;  sy[n0]     = ld0.y;                                   \
    sx[n0 + 1] = ld1.y;  sy[n0 + 1] = ld2.x;                                   \
    pzp##j.x   = ld1.x;  pzp##j.y   = ld2.y;                                   \
    asm volatile("" : "+v"(pzp##j)); }
  R8M(FPS_LOADP)

  float cz = xb[2];
  __syncthreads();
  float cx = sx[0], cy = sy[0];
  int sel = 0, msel = 0;

  for (int iter = 0; iter < P; ++iter) {
    msel = (t == iter) ? sel : msel;
    if (iter == P - 1) break;

    v2f cxx, cyy, czz;
    { float v = negf(cx); cxx.x = v; cxx.y = v; }
    { float v = negf(cy); cyy.x = v; cyy.y = v; }
    { float v = negf(cz); czz.x = v; czz.y = v; }

    v2f sq0, sq1, sq2, sq3, sq4, sq5, sq6, sq7;
#define FPS_XY(i, ja, jb) {                                                    \
      const int n0 = (t << 2) + ((i) << 12);                                   \
      v2f xl = *(const v2f*)&sx[n0];  v2f xh = *(const v2f*)&sx[n0 + 2];       \
      v2f yl = *(const v2f*)&sy[n0];  v2f yh = *(const v2f*)&sy[n0 + 2];       \
      v2f dxl = pk_add(xl, cxx), dyl = pk_add(yl, cyy);                        \
      v2f dxh = pk_add(xh, cxx), dyh = pk_add(yh, cyy);                        \
      sq##ja = pk_add(pk_mul(dxl, dxl), pk_mul(dyl, dyl));                     \
      sq##jb = pk_add(pk_mul(dxh, dxh), pk_mul(dyh, dyh)); }
    FPS_XY(0, 0, 1)
    FPS_XY(1, 2, 3)
    FPS_XY(2, 4, 5)
    FPS_XY(3, 6, 7)

    float bestv = -1.0f;
    int   s = 0;
#define FPS_Z(j) {                                                             \
      v2f dz = pk_add(pzp##j, czz);                                            \
      v2f dd = pk_add(sq##j, pk_mul(dz, dz));                                  \
      dmp##j.x = fminf(dmp##j.x, dd.x);                                        \
      dmp##j.y = fminf(dmp##j.y, dd.y);                                        \
      bool b0 = dmp##j.x > bestv;                                              \
      bestv = b0 ? dmp##j.x : bestv;  s = b0 ? (2 * (j))     : s;              \
      bool b1 = dmp##j.y > bestv;                                              \
      bestv = b1 ? dmp##j.y : bestv;  s = b1 ? (2 * (j) + 1) : s; }
    R8M(FPS_Z)

    float wm = bestv;
    wm = dpp_fmax<0xB1>(wm);
    wm = dpp_fmax<0x4E>(wm);
    wm = dpp_fmax<0x141>(wm);
    wm = dpp_fmax<0x140>(wm);
    wm = dpp_fmax<0x142>(wm);
    wm = dpp_fmax<0x143>(wm);
    const float wmax = __int_as_float(
        __builtin_amdgcn_readlane(__float_as_int(wm), 63));

    if (bestv == wmax) {
      int nn = (t << 2) + ((s & 12) << 10) + (s & 3);        // 14 bits
      unsigned inv = ~__float_as_uint(bestv);                // desc in val
      ull key = ((ull)(unsigned)(P - 1 - iter) << 46) |
                ((ull)inv << 14) | (ull)(unsigned)nn;
      atomicMin(&slot[iter & 1], key);
    }
    __syncthreads();

    ull k = slot[iter & 1];
    sel = __builtin_amdgcn_readfirstlane((int)((unsigned)k & 0x3FFFu));
    cx = sx[sel];
    cy = sy[sel];
    cz = xb[(size_t)sel * 3 + 2];
  }

  {
    const int n = msel;
    size_t o = ((size_t)b * P + t) * 3;
    new_xyz[o + 0] = sx[n];
    new_xyz[o + 1] = sy[n];
    new_xyz[o + 2] = xb[(size_t)n * 3 + 2];
  }
#undef FPS_DECL
#undef FPS_LOADP
#undef FPS_XY
#undef FPS_Z
}

// ================= kernel 2: fused ballq + MLPs, one item per wave ========
// consumer LDS layout (byte offsets into 108160B pool):
//  0      W10 [35][32]   4480 |  4480  W20 [32][64]   8192
//  12672  W11 [35][64]   8960 | 21632  W21 [64][128] 32768
//  54400  scale/bias     2304 | 56704  4x per-wave  51456  (end 108160)
// per-wave region: idx0 16i + idx1 32i (192B), xs 35x32 (4480B),
// o1s 64x32 (8192B) = 12864B.
#define OFF_W10 0
#define OFF_W20 4480
#define OFF_W11 12672
#define OFF_W21 21632
#define OFF_SB  54400
#define OFF_PW  56704
#define PW_SZ   12864

// Bitwise == R9 mlp: per-(o,s) single fmaf chain over ascending c, then
// fmaf(acc,scale,bias); relu floor fmax(..,0); max over ascending s.
template <int S, int C1, int C2>
__device__ void wave_mlp(const int lane, const int* __restrict__ ip,
                         const float* __restrict__ xb,
                         const float* __restrict__ fb,
                         const float cx, const float cy, const float cz,
                         const float* __restrict__ wl1,
                         const float* __restrict__ wl2,
                         const float* __restrict__ s1v,
                         const float* __restrict__ b1v,
                         const float* __restrict__ s2v,
                         const float* __restrict__ b2v,
                         float* __restrict__ xs, float* __restrict__ o1s,
                         float* __restrict__ outp)
{
  // gather: xyz-diff channels + contiguous float4 feature rows
  for (int s = lane; s < S; s += 64) {
    const int n = ip[s];
    xs[0 * S + s] = xb[n * 3 + 0] - cx;
    xs[1 * S + s] = xb[n * 3 + 1] - cy;
    xs[2 * S + s] = xb[n * 3 + 2] - cz;
  }
  for (int i = lane; i < S * 8; i += 64) {
    const int s = i >> 3, q = i & 7;
    const int n = ip[s];
    const float4 v = *(const float4*)&fb[(size_t)n * 32 + q * 4];
    const int c = 3 + q * 4;
    xs[(c + 0) * S + s] = v.x; xs[(c + 1) * S + s] = v.y;
    xs[(c + 2) * S + s] = v.z; xs[(c + 3) * S + s] = v.w;
  }
  // layer 1: lane -> (s = lane%S, group of OPL outputs); 8 accs per pass
  {
    const int s   = lane % S;
    const int grp = lane / S;
    constexpr int OPL = (C1 * S) / 64;
    constexpr int NP  = (OPL < 8) ? OPL : 8;
    const int ob0 = grp * OPL;
#pragma unroll
    for (int pass = 0; pass < OPL / NP; ++pass) {
      const int ob = ob0 + pass * NP;
      float acc[NP];
#pragma unroll
      for (int j = 0; j < NP; ++j) acc[j] = 0.0f;
      for (int c = 0; c < 35; ++c) {
        const float xv = xs[c * S + s];
#pragma unroll
        for (int j4 = 0; j4 < NP / 4; ++j4) {
          const float4 w4 = *(const float4*)&wl1[c * C1 + ob + 4 * j4];
          acc[4 * j4 + 0] = fmaf(xv, w4.x, acc[4 * j4 + 0]);
          acc[4 * j4 + 1] = fmaf(xv, w4.y, acc[4 * j4 + 1]);
          acc[4 * j4 + 2] = fmaf(xv, w4.z, acc[4 * j4 + 2]);
          acc[4 * j4 + 3] = fmaf(xv, w4.w, acc[4 * j4 + 3]);
        }
      }
#pragma unroll
      for (int j = 0; j < NP; ++j) {
        const int o = ob + j;
        o1s[o * S + s] = fmaxf(fmaf(acc[j], s1v[o], b1v[o]), 0.0f);
      }
    }
  }
  // layer 2 + max over s: lane owns o2 = lane (+64); 16-wide s blocks
  {
#pragma unroll
    for (int k = 0; k < C2 / 64; ++k) {
      const int o2 = lane + 64 * k;
      const float sc = s2v[o2], bi = b2v[o2];
      float m = 0.0f;   // relu floor
#pragma unroll
      for (int sb0 = 0; sb0 < S / 16; ++sb0) {
        float acc[16];
#pragma unroll
        for (int j = 0; j < 16; ++j) acc[j] = 0.0f;
        for (int c = 0; c < C1; ++c) {
          const float wv = wl2[c * C2 + o2];
#pragma unroll
          for (int j4 = 0; j4 < 4; ++j4) {
            const float4 ov = *(const float4*)&o1s[c * S + sb0 * 16 + 4 * j4];
            acc[4 * j4 + 0] = fmaf(ov.x, wv, acc[4 * j4 + 0]);
            acc[4 * j4 + 1] = fmaf(ov.y, wv, acc[4 * j4 + 1]);
            acc[4 * j4 + 2] = fmaf(ov.z, wv, acc[4 * j4 + 2]);
            acc[4 * j4 + 3] = fmaf(ov.w, wv, acc[4 * j4 + 3]);
          }
        }
#pragma unroll
        for (int j = 0; j < 16; ++j) m = fmaxf(m, fmaf(acc[j], sc, bi));
      }
      outp[(size_t)o2 * P] = m;
    }
  }
}

__global__ __launch_bounds__(256)
void fused_kernel(const float* __restrict__ xyz,
                  const float* __restrict__ ftr,
                  const float* __restrict__ sox, const float* __restrict__ soy,
                  const float* __restrict__ soz,
                  const float* __restrict__ new_xyz,
                  const float* __restrict__ w00, const float* __restrict__ s00,
                  const float* __restrict__ b00, const float* __restrict__ w01,
                  const float* __restrict__ s01, const float* __restrict__ b01,
                  const float* __restrict__ w10, const float* __restrict__ s10,
                  const float* __restrict__ b10, const float* __restrict__ w11,
                  const float* __restrict__ s11, const float* __restrict__ b11,
                  float* __restrict__ feat_out)
{
  __shared__ __align__(16) char smem[108160];
  const int t = threadIdx.x;

  // ---- stage weights (transposed) + scale/bias into LDS ----
  float* W10 = (float*)(smem + OFF_W10);
  float* W20 = (float*)(smem + OFF_W20);
  float* W11 = (float*)(smem + OFF_W11);
  float* W21 = (float*)(smem + OFF_W21);
  float* SBv = (float*)(smem + OFF_SB);
  float* SB10s = SBv;        float* SB10b = SBv + 32;
  float* SB20s = SBv + 64;   float* SB20b = SBv + 128;
  float* SB11s = SBv + 192;  float* SB11b = SBv + 256;
  float* SB21s = SBv + 320;  float* SB21b = SBv + 448;

  for (int i = t; i < 35 * 32; i += 256) {
    const int o = i % 32, c = i / 32;
    W10[c * 32 + o] = w00[o * 35 + c];
  }
  for (int i = t; i < 32 * 64; i += 256) {
    const int c = i >> 6, o = i & 63;
    W20[c * 64 + o] = w01[o * 32 + c];
  }
  for (int i = t; i < 35 * 64; i += 256) {
    const int o = i % 64, c = i / 64;
    W11[c * 64 + o] = w10[o * 35 + c];
  }
  for (int i = t; i < 64 * 128; i += 256) {
    const int c = i >> 7, o = i & 127;
    W21[c * 128 + o] = w11[o * 64 + c];
  }
  if (t < 32)  { SB10s[t] = s00[t]; SB10b[t] = b00[t]; }
  if (t < 64)  { SB20s[t] = s01[t]; SB20b[t] = b01[t];
                 SB11s[t] = s10[t]; SB11b[t] = b10[t]; }
  if (t < 128) { SB21s[t] = s11[t]; SB21b[t] = b11[t]; }
  __syncthreads();
  // ---- after this point: wave-synchronous only, zero barriers ----

  const int wv   = t >> 6;
  const int lane = t & 63;
  const int wid  = blockIdx.x * 4 + wv;      // item id, 0..8191
  const int bb = wid >> 10;
  const int p  = wid & (P - 1);

  int*   widx0 = (int*)(smem + OFF_PW + wv * PW_SZ);
  int*   widx1 = widx0 + 16;
  float* wxs   = (float*)(smem + OFF_PW + wv * PW_SZ + 192);
  float* wo1   = wxs + 35 * 32;

  const size_t bp = (size_t)bb * P + p;
  const float cx = new_xyz[bp * 3 + 0];
  const float cy = new_xyz[bp * 3 + 1];
  const float cz = new_xyz[bp * 3 + 2];

  // ---- ballq (R9 logic, dense SoA float4, idx into wave LDS) ----
  {
    const float* X = sox + (size_t)bb * N;
    const float* Y = soy + (size_t)bb * N;
    const float* Z = soz + (size_t)bb * N;
    const float qv = __fadd_rn(__fadd_rn(__fmul_rn(cx, cx), __fmul_rn(cy, cy)),
                               __fmul_rn(cz, cz));
    int c0 = 0, c1 = 0, f0 = 0, f1 = 0;
    const ull below = (1ull << lane) - 1ull;

    for (int base = 0; base < N; base += 256) {
      const int n0 = base + (lane << 2);
      const float4 xv = *(const float4*)&X[n0];
      const float4 yv = *(const float4*)&Y[n0];
      const float4 zv = *(const float4*)&Z[n0];
      float d2[4];
#pragma unroll
      for (int e = 0; e < 4; ++e) {
        const float x = (e == 0) ? xv.x : (e == 1) ? xv.y : (e == 2) ? xv.z : xv.w;
        const float y = (e == 0) ? yv.x : (e == 1) ? yv.y : (e == 2) ? yv.z : yv.w;
        const float z = (e == 0) ? zv.x : (e == 1) ? zv.y : (e == 2) ? zv.z : zv.w;
        const float xx = __fadd_rn(__fadd_rn(__fmul_rn(x, x), __fmul_rn(y, y)),
                                   __fmul_rn(z, z));
        const float dot = __fadd_rn(__fadd_rn(__fmul_rn(cx, x), __fmul_rn(cy, y)),
                                    __fmul_rn(cz, z));
        d2[e] = __fsub_rn(__fadd_rn(qv, xx), __fmul_rn(2.0f, dot));
      }
      ull m0[4], m1[4];
#pragma unroll
      for (int e = 0; e < 4; ++e) {
        m0[e] = __ballot(d2[e] < 0.25f);
        m1[e] = __ballot(d2[e] < 1.0f);
      }
#define BQ_PROC(m, cap, oarr, cnt, fst) {                                      \
      const int tot = (int)(__builtin_popcountll(m[0]) +                       \
                            __builtin_popcountll(m[1]) +                       \
                            __builtin_popcountll(m[2]) +                       \
                            __builtin_popcountll(m[3]));                       \
      if (cnt < cap && tot) {                                                  \
        if (cnt == 0) {                                                        \
          const ull any = m[0] | m[1] | m[2] | m[3];                           \
          const int lm = __builtin_ctzll(any);                                 \
          const int em = ((m[0] >> lm) & 1ull) ? 0 :                           \
                         ((m[1] >> lm) & 1ull) ? 1 :                           \
                         ((m[2] >> lm) & 1ull) ? 2 : 3;                        \
          fst = base + (lm << 2) + em;                                         \
        }                                                                      \
        int pos = cnt + (int)(__builtin_popcountll(m[0] & below) +             \
                              __builtin_popcountll(m[1] & below) +             \
                              __builtin_popcountll(m[2] & below) +             \
                              __builtin_popcountll(m[3] & below));             \
        const bool h0 = (m[0] >> lane) & 1ull;                                 \
        const bool h1 = (m[1] >> lane) & 1ull;                                 \
        const bool h2 = (m[2] >> lane) & 1ull;                                 \
        const bool h3 = (m[3] >> lane) & 1ull;                                 \
        if (h0 && pos < cap) oarr[pos] = n0 + 0;                               \
        pos += h0;                                                             \
        if (h1 && pos < cap) oarr[pos] = n0 + 1;                               \
        pos += h1;                                                             \
        if (h2 && pos < cap) oarr[pos] = n0 + 2;                               \
        pos += h2;                                                             \
        if (h3 && pos < cap) oarr[pos] = n0 + 3;                               \
      }                                                                        \
      cnt = min(cap, cnt + tot); }
      BQ_PROC(m0, 16, widx0, c0, f0)
      BQ_PROC(m1, 32, widx1, c1, f1)
#undef BQ_PROC
      if (c0 >= 16 && c1 >= 32) break;
    }
    for (int s = c0 + lane; s < 16; s += 64) widx0[s] = f0;
    for (int s = c1 + lane; s < 32; s += 64) widx1[s] = f1;
  }

  // ---- fused MLP branches (wave-synchronous, idx/xs/o1s stay in LDS) ----
  const float* xb2 = xyz + (size_t)bb * (N * 3);
  const float* fb2 = ftr + (size_t)bb * N * 32;
  float* outp0 = feat_out + ((size_t)bb * 192 + 0) * P + p;
  float* outp1 = feat_out + ((size_t)bb * 192 + 64) * P + p;
  wave_mlp<16, 32, 64>(lane, widx0, xb2, fb2, cx, cy, cz,
                       W10, W20, SB10s, SB10b, SB20s, SB20b,
                       wxs, wo1, outp0);
  wave_mlp<32, 64, 128>(lane, widx1, xb2, fb2, cx, cy, cz,
                        W11, W21, SB11s, SB11b, SB21s, SB21b,
                        wxs, wo1, outp1);
}

extern "C" void kernel_launch(void* const* d_in, const int* in_sizes, int n_in,
                              void* d_out, int out_size, void* d_ws, size_t ws_size,
                              hipStream_t stream) {
  const float* xyz   = (const float*)d_in[0];
  const float* feats = (const float*)d_in[1];
  const float* w0_0 = (const float*)d_in[2];
  const float* s0_0 = (const float*)d_in[3];
  const float* b0_0 = (const float*)d_in[4];
  const float* w0_1 = (const float*)d_in[5];
  const float* s0_1 = (const float*)d_in[6];
  const float* b0_1 = (const float*)d_in[7];
  const float* w1_0 = (const float*)d_in[8];
  const float* s1_0 = (const float*)d_in[9];
  const float* b1_0 = (const float*)d_in[10];
  const float* w1_1 = (const float*)d_in[11];
  const float* s1_1 = (const float*)d_in[12];
  const float* b1_1 = (const float*)d_in[13];

  float* out      = (float*)d_out;
  float* new_xyz  = out;                      // (B,P,3)
  float* feat_out = out + (size_t)B * P * 3;  // (B,192,P)

  char* w = (char*)d_ws;
  float* ftr = (float*)w; w += (size_t)B * N * 32 * sizeof(float);  // 16 MB
  float* sox = (float*)w; w += (size_t)B * N * sizeof(float);
  float* soy = (float*)w; w += (size_t)B * N * sizeof(float);
  float* soz = (float*)w; w += (size_t)B * N * sizeof(float);

  fps_prep_kernel<<<dim3(8 + B * (N / 256)), dim3(1024), 0, stream>>>(
      xyz, feats, new_xyz, ftr, sox, soy, soz);
  fused_kernel<<<dim3(B * P / 4), dim3(256), 0, stream>>>(
      xyz, ftr, sox, soy, soz, new_xyz,
      w0_0, s0_0, b0_0, w0_1, s0_1, b0_1,
      w1_0, s1_0, b1_0, w1_1, s1_1, b1_1, feat_out);
}

// Round 13
// 2197.381 us; speedup vs baseline: 1.0755x; 1.0755x over previous
//
#include <hip/hip_runtime.h>

#define B 8
#define N 16384
#define C_IN 32
#define P 1024

typedef float v2f __attribute__((ext_vector_type(2)));
typedef unsigned long long ull;

// ---------------------------------------------------------------------------
// R13 = R9 revert (best verified: 2192us). Structure:
//  1) fps_prep_kernel: blocks 0..7 = frozen-R7 FPS (~1810us, measured floor
//     across 4 structural variants); blocks 8..519 = transpose+SoA prep,
//     fully hidden under the FPS shadow (verified R9/R12 counters).
//  2) ballq_kernel: SoA dense float4, 4 pts/lane, ballot+prefix-popcount.
//  3) mlp_kernel x2: transposed-feature gather, padded wl2, pk-fma.
// R10/R11 (persistent-wave fusion) killed containers; R12 (wave-per-item
// fusion) regressed to 2363 (1 wave/SIMD occupancy collapse). This split is
// the measured optimum.
// ---------------------------------------------------------------------------
#define R8M(OP) OP(0) OP(1) OP(2) OP(3) OP(4) OP(5) OP(6) OP(7)

__device__ __forceinline__ v2f pk_add(v2f a, v2f b) {
  v2f d; asm("v_pk_add_f32 %0, %1, %2" : "=v"(d) : "v"(a), "v"(b)); return d;
}
__device__ __forceinline__ v2f pk_mul(v2f a, v2f b) {
  v2f d; asm("v_pk_mul_f32 %0, %1, %2" : "=v"(d) : "v"(a), "v"(b)); return d;
}
__device__ __forceinline__ float negf(float x) {
  return __int_as_float(__float_as_int(x) ^ 0x80000000);
}
template <int CTRL>
__device__ __forceinline__ float dpp_fmax(float v) {
  float o = __int_as_float(__builtin_amdgcn_update_dpp(
      __float_as_int(v), __float_as_int(v), CTRL, 0xF, 0xF, false));
  return fmaxf(v, o);
}

__global__ __launch_bounds__(1024)
void fps_prep_kernel(const float* __restrict__ xyz,
                     const float* __restrict__ feats,
                     float* __restrict__ new_xyz,
                     float* __restrict__ ftr,
                     float* __restrict__ sox, float* __restrict__ soy,
                     float* __restrict__ soz)
{
  __shared__ __align__(16) char smem[131088];
  const int t = threadIdx.x;

  if (blockIdx.x >= 8) {
    // ---------------- prep path: transpose + SoA ----------------
    const int pid   = blockIdx.x - 8;          // 0..511
    const int pb    = pid >> 6;                // batch
    const int n0    = (pid & 63) << 8;         // 256-point chunk
    const float* fb = feats + (size_t)pb * (C_IN * N);
    const float* xb = xyz + (size_t)pb * (N * 3);
    float (*tile)[257] = (float(*)[257])smem;

    {
      const int c  = t >> 5;            // 0..31
      const int nn = (t & 31) << 3;     // 0..248
      const float* src = fb + (size_t)c * N + n0 + nn;
      const float4 a0 = *(const float4*)(src);
      const float4 a1 = *(const float4*)(src + 4);
      tile[c][nn + 0] = a0.x; tile[c][nn + 1] = a0.y;
      tile[c][nn + 2] = a0.z; tile[c][nn + 3] = a0.w;
      tile[c][nn + 4] = a1.x; tile[c][nn + 5] = a1.y;
      tile[c][nn + 6] = a1.z; tile[c][nn + 7] = a1.w;
    }
    if (t < 256) {
      const int n = n0 + t;
      const size_t o = (size_t)pb * N + n;
      sox[o] = xb[(size_t)n * 3 + 0];
      soy[o] = xb[(size_t)n * 3 + 1];
      soz[o] = xb[(size_t)n * 3 + 2];
    }
    __syncthreads();
    {
      const int n  = t >> 2;            // 0..255
      const int c0 = (t & 3) << 3;      // 0,8,16,24
      float4 o0, o1;
      o0.x = tile[c0 + 0][n]; o0.y = tile[c0 + 1][n];
      o0.z = tile[c0 + 2][n]; o0.w = tile[c0 + 3][n];
      o1.x = tile[c0 + 4][n]; o1.y = tile[c0 + 5][n];
      o1.z = tile[c0 + 6][n]; o1.w = tile[c0 + 7][n];
      float4* dst = (float4*)(ftr + ((size_t)pb * N + n0 + n) * 32 + c0);
      dst[0] = o0;
      dst[1] = o1;
    }
    return;
  }

  // ---------------- FPS path (frozen R7 logic) ----------------
  float* sx = (float*)smem;
  float* sy = sx + N;
  ull*  slot = (ull*)(smem + 2 * N * sizeof(float));

  const int b = blockIdx.x;
  const float* xb = xyz + (size_t)b * (N * 3);

  if (t == 0) { slot[0] = ~0ull; slot[1] = ~0ull; }

#define FPS_DECL(j) v2f pzp##j, dmp##j; dmp##j.x = 1e10f; dmp##j.y = 1e10f;
  R8M(FPS_DECL)
#define FPS_LOADP(j) {                                                         \
    const int n0 = (t << 2) + ((j >> 1) << 12) + ((j & 1) << 1);               \
    const float2 ld0 = *(const float2*)&xb[(size_t)n0 * 3 + 0];                \
    const float2 ld1 = *(const float2*)&xb[(size_t)n0 * 3 + 2];                \
    const float2 ld2 = *(const float2*)&xb[(size_t)n0 * 3 + 4];                \
    sx[n0]     = ld0.x;  sy[n0]     = ld0.y;                                   \
    sx[n0 + 1] = ld1.y;  sy[n0 + 1] = ld2.x;                                   \
    pzp##j.x   = ld1.x;  pzp##j.y   = ld2.y;                                   \
    asm volatile("" : "+v"(pzp##j)); }
  R8M(FPS_LOADP)

  float cz = xb[2];
  __syncthreads();
  float cx = sx[0], cy = sy[0];
  int sel = 0, msel = 0;

  for (int iter = 0; iter < P; ++iter) {
    msel = (t == iter) ? sel : msel;
    if (iter == P - 1) break;

    v2f cxx, cyy, czz;
    { float v = negf(cx); cxx.x = v; cxx.y = v; }
    { float v = negf(cy); cyy.x = v; cyy.y = v; }
    { float v = negf(cz); czz.x = v; czz.y = v; }

    v2f sq0, sq1, sq2, sq3, sq4, sq5, sq6, sq7;
#define FPS_XY(i, ja, jb) {                                                    \
      const int n0 = (t << 2) + ((i) << 12);                                   \
      v2f xl = *(const v2f*)&sx[n0];  v2f xh = *(const v2f*)&sx[n0 + 2];       \
      v2f yl = *(const v2f*)&sy[n0];  v2f yh = *(const v2f*)&sy[n0 + 2];       \
      v2f dxl = pk_add(xl, cxx), dyl = pk_add(yl, cyy);                        \
      v2f dxh = pk_add(xh, cxx), dyh = pk_add(yh, cyy);                        \
      sq##ja = pk_add(pk_mul(dxl, dxl), pk_mul(dyl, dyl));                     \
      sq##jb = pk_add(pk_mul(dxh, dxh), pk_mul(dyh, dyh)); }
    FPS_XY(0, 0, 1)
    FPS_XY(1, 2, 3)
    FPS_XY(2, 4, 5)
    FPS_XY(3, 6, 7)

    float bestv = -1.0f;
    int   s = 0;
#define FPS_Z(j) {                                                             \
      v2f dz = pk_add(pzp##j, czz);                                            \
      v2f dd = pk_add(sq##j, pk_mul(dz, dz));                                  \
      dmp##j.x = fminf(dmp##j.x, dd.x);                                        \
      dmp##j.y = fminf(dmp##j.y, dd.y);                                        \
      bool b0 = dmp##j.x > bestv;                                              \
      bestv = b0 ? dmp##j.x : bestv;  s = b0 ? (2 * (j))     : s;              \
      bool b1 = dmp##j.y > bestv;                                              \
      bestv = b1 ? dmp##j.y : bestv;  s = b1 ? (2 * (j) + 1) : s; }
    R8M(FPS_Z)

    float wm = bestv;
    wm = dpp_fmax<0xB1>(wm);
    wm = dpp_fmax<0x4E>(wm);
    wm = dpp_fmax<0x141>(wm);
    wm = dpp_fmax<0x140>(wm);
    wm = dpp_fmax<0x142>(wm);
    wm = dpp_fmax<0x143>(wm);
    const float wmax = __int_as_float(
        __builtin_amdgcn_readlane(__float_as_int(wm), 63));

    if (bestv == wmax) {
      int nn = (t << 2) + ((s & 12) << 10) + (s & 3);        // 14 bits
      unsigned inv = ~__float_as_uint(bestv);                // desc in val
      ull key = ((ull)(unsigned)(P - 1 - iter) << 46) |
                ((ull)inv << 14) | (ull)(unsigned)nn;
      atomicMin(&slot[iter & 1], key);
    }
    __syncthreads();

    ull k = slot[iter & 1];
    sel = __builtin_amdgcn_readfirstlane((int)((unsigned)k & 0x3FFFu));
    cx = sx[sel];
    cy = sy[sel];
    cz = xb[(size_t)sel * 3 + 2];
  }

  {
    const int n = msel;
    size_t o = ((size_t)b * P + t) * 3;
    new_xyz[o + 0] = sx[n];
    new_xyz[o + 1] = sy[n];
    new_xyz[o + 2] = xb[(size_t)n * 3 + 2];
  }
#undef FPS_DECL
#undef FPS_LOADP
#undef FPS_XY
#undef FPS_Z
}

// ---------------------------------------------------------------------------
// Ball query: SoA inputs, 4 points/lane (256 points/round/wave), dense
// float4 loads. Exact first-nsample-in-ascending-index semantics via
// ballot + prefix popcount; pad = first hit (0 if none). Distance math
// bitwise identical: (qv+xx) - 2*dot, all __f*_rn.
// ---------------------------------------------------------------------------
__global__ __launch_bounds__(256) void ballq_kernel(
    const float* __restrict__ sox, const float* __restrict__ soy,
    const float* __restrict__ soz, const float* __restrict__ new_xyz,
    int* __restrict__ idx0, int* __restrict__ idx1)
{
  const int wid  = blockIdx.x * 4 + (threadIdx.x >> 6);
  const int lane = threadIdx.x & 63;
  const int b = wid >> 10;
  const int p = wid & (P - 1);
  const float* X = sox + (size_t)b * N;
  const float* Y = soy + (size_t)b * N;
  const float* Z = soz + (size_t)b * N;
  const size_t bp = (size_t)b * P + p;
  const float cx = new_xyz[bp * 3 + 0];
  const float cy = new_xyz[bp * 3 + 1];
  const float cz = new_xyz[bp * 3 + 2];
  const float qv = __fadd_rn(__fadd_rn(__fmul_rn(cx, cx), __fmul_rn(cy, cy)),
                             __fmul_rn(cz, cz));
  int* __restrict__ o0 = idx0 + bp * 16;
  int* __restrict__ o1 = idx1 + bp * 32;

  int c0 = 0, c1 = 0, f0 = 0, f1 = 0;
  const ull below = (1ull << lane) - 1ull;

  for (int base = 0; base < N; base += 256) {
    const int n0 = base + (lane << 2);
    const float4 xv = *(const float4*)&X[n0];
    const float4 yv = *(const float4*)&Y[n0];
    const float4 zv = *(const float4*)&Z[n0];

    float d2[4];
#pragma unroll
    for (int e = 0; e < 4; ++e) {
      const float x = (e == 0) ? xv.x : (e == 1) ? xv.y : (e == 2) ? xv.z : xv.w;
      const float y = (e == 0) ? yv.x : (e == 1) ? yv.y : (e == 2) ? yv.z : yv.w;
      const float z = (e == 0) ? zv.x : (e == 1) ? zv.y : (e == 2) ? zv.z : zv.w;
      const float xx = __fadd_rn(__fadd_rn(__fmul_rn(x, x), __fmul_rn(y, y)),
                                 __fmul_rn(z, z));
      const float dot = __fadd_rn(__fadd_rn(__fmul_rn(cx, x), __fmul_rn(cy, y)),
                                  __fmul_rn(cz, z));
      d2[e] = __fsub_rn(__fadd_rn(qv, xx), __fmul_rn(2.0f, dot));
    }

    ull m0[4], m1[4];
#pragma unroll
    for (int e = 0; e < 4; ++e) {
      m0[e] = __ballot(d2[e] < 0.25f);
      m1[e] = __ballot(d2[e] < 1.0f);
    }

#define BQ_PROC(m, cap, oarr, cnt, fst) {                                      \
    const int tot = (int)(__builtin_popcountll(m[0]) +                         \
                          __builtin_popcountll(m[1]) +                         \
                          __builtin_popcountll(m[2]) +                         \
                          __builtin_popcountll(m[3]));                         \
    if (cnt < cap && tot) {                                                    \
      if (cnt == 0) {                                                          \
        const ull any = m[0] | m[1] | m[2] | m[3];                             \
        const int lm = __builtin_ctzll(any);                                   \
        const int em = ((m[0] >> lm) & 1ull) ? 0 :                             \
                       ((m[1] >> lm) & 1ull) ? 1 :                             \
                       ((m[2] >> lm) & 1ull) ? 2 : 3;                          \
        fst = base + (lm << 2) + em;                                           \
      }                                                                        \
      int pos = cnt + (int)(__builtin_popcountll(m[0] & below) +               \
                            __builtin_popcountll(m[1] & below) +               \
                            __builtin_popcountll(m[2] & below) +               \
                            __builtin_popcountll(m[3] & below));               \
      const bool h0 = (m[0] >> lane) & 1ull;                                   \
      const bool h1 = (m[1] >> lane) & 1ull;                                   \
      const bool h2 = (m[2] >> lane) & 1ull;                                   \
      const bool h3 = (m[3] >> lane) & 1ull;                                   \
      if (h0 && pos < cap) oarr[pos] = n0 + 0;                                 \
      pos += h0;                                                               \
      if (h1 && pos < cap) oarr[pos] = n0 + 1;                                 \
      pos += h1;                                                               \
      if (h2 && pos < cap) oarr[pos] = n0 + 2;                                 \
      pos += h2;                                                               \
      if (h3 && pos < cap) oarr[pos] = n0 + 3;                                 \
    }                                                                          \
    cnt = min(cap, cnt + tot); }

    BQ_PROC(m0, 16, o0, c0, f0)
    BQ_PROC(m1, 32, o1, c1, f1)
#undef BQ_PROC
    if (c0 >= 16 && c1 >= 32) break;
  }
  for (int s = c0 + lane; s < 16; s += 64) o0[s] = f0;
  for (int s = c1 + lane; s < 32; s += 64) o1[s] = f1;
}

// ---------------------------------------------------------------------------
// Fused grouping + conv1 + conv2 + max (R8 form, passing):
// transposed-feature float4 gather, padded wl2, pk-fma over o/s pairs;
// per-(o,s) c-chain order unchanged -> bitwise-identical output.
// ---------------------------------------------------------------------------
template <int S, int C1, int C2, int CH_OFF>
__global__ __launch_bounds__(256) void mlp_kernel(
    const float* __restrict__ xyz, const float* __restrict__ ftr,
    const float* __restrict__ new_xyz, const int* __restrict__ idx,
    const float* __restrict__ w1, const float* __restrict__ s1,
    const float* __restrict__ b1, const float* __restrict__ w2,
    const float* __restrict__ s2, const float* __restrict__ b2,
    float* __restrict__ out)
{
  static_assert((C1 * S) % 512 == 0 && (C2 * S) % 512 == 0, "mapping");
  __shared__ float wl1[35][C1];      // wl1[c][o] = w1[o][c]
  __shared__ float wl2[C1][C2 + 1];  // wl2[c][o] = w2[o][c], padded row
  __shared__ float sb1[2][C1];
  __shared__ float sb2[2][C2];
  __shared__ float xs[35][S];
  __shared__ float o1s[C1][S];
  __shared__ float pm[256];

  const int tid = threadIdx.x;
  for (int i = tid; i < 35 * C1; i += 256) {
    int o = i % C1, c = i / C1;
    wl1[c][o] = w1[o * 35 + c];
  }
  for (int i = tid; i < (C1 * C2) / 4; i += 256) {
    const float4 v = *(const float4*)&w2[i * 4];
    const int o = (i * 4) / C1, c = (i * 4) % C1;
    wl2[c + 0][o] = v.x; wl2[c + 1][o] = v.y;
    wl2[c + 2][o] = v.z; wl2[c + 3][o] = v.w;
  }
  if (tid < C1) { sb1[0][tid] = s1[tid]; sb1[1][tid] = b1[tid]; }
  if (tid < C2) { sb2[0][tid] = s2[tid]; sb2[1][tid] = b2[tid]; }

  const int b  = blockIdx.x / (P / 8);
  const int p0 = (blockIdx.x % (P / 8)) * 8;
  const float* xb = xyz + (size_t)b * (N * 3);
  const float* fb = ftr + (size_t)b * N * 32;
  __syncthreads();

  for (int pi = 0; pi < 8; ++pi) {
    const int p = p0 + pi;
    const size_t bp = (size_t)b * P + p;
    const int* ip = idx + bp * S;
    const float cx = new_xyz[bp * 3 + 0];
    const float cy = new_xyz[bp * 3 + 1];
    const float cz = new_xyz[bp * 3 + 2];
    for (int s2i = tid; s2i < S; s2i += 256) {
      const int n = ip[s2i];
      xs[0][s2i] = xb[n * 3 + 0] - cx;
      xs[1][s2i] = xb[n * 3 + 1] - cy;
      xs[2][s2i] = xb[n * 3 + 2] - cz;
    }
    for (int i = tid; i < S * 8; i += 256) {
      const int s = i >> 3, q = i & 7;
      const int n = ip[s];
      const float4 v = *(const float4*)&fb[(size_t)n * 32 + q * 4];
      const int c = 3 + q * 4;
      xs[c + 0][s] = v.x; xs[c + 1][s] = v.y;
      xs[c + 2][s] = v.z; xs[c + 3][s] = v.w;
    }
    __syncthreads();
    {
      constexpr int OPT  = (C1 * S) / 256;
      constexpr int OPT2 = OPT / 2;
      const int s  = tid % S;
      const int ob = (tid / S) * OPT;
      v2f acc[OPT2];
#pragma unroll
      for (int m = 0; m < OPT2; ++m) { acc[m].x = 0.0f; acc[m].y = 0.0f; }
      for (int c = 0; c < 35; ++c) {
        const float xv = xs[c][s];
        v2f xv2; xv2.x = xv; xv2.y = xv;
#pragma unroll
        for (int m = 0; m < OPT2; ++m) {
          const v2f w = *(const v2f*)&wl1[c][ob + 2 * m];
          asm("v_pk_fma_f32 %0, %1, %2, %0"
              : "+v"(acc[m]) : "v"(xv2), "v"(w));
        }
      }
#pragma unroll
      for (int m = 0; m < OPT2; ++m) {
        const int o0i = ob + 2 * m, o1i = ob + 2 * m + 1;
        float v0 = fmaf(acc[m].x, sb1[0][o0i], sb1[1][o0i]);
        float v1 = fmaf(acc[m].y, sb1[0][o1i], sb1[1][o1i]);
        o1s[o0i][s] = fmaxf(v0, 0.0f);
        o1s[o1i][s] = fmaxf(v1, 0.0f);
      }
    }
    __syncthreads();
    {
      constexpr int NS  = (C2 * S) / 256;
      constexpr int NS2 = NS / 2;
      const int o2 = tid % C2;
      const int sb = (tid / C2) * NS;
      v2f acc[NS2];
#pragma unroll
      for (int m = 0; m < NS2; ++m) { acc[m].x = 0.0f; acc[m].y = 0.0f; }
      for (int c = 0; c < C1; ++c) {
        const float wv = wl2[c][o2];
        v2f wv2; wv2.x = wv; wv2.y = wv;
#pragma unroll
        for (int m = 0; m < NS2; ++m) {
          const v2f ov = *(const v2f*)&o1s[c][sb + 2 * m];
          asm("v_pk_fma_f32 %0, %1, %2, %0"
              : "+v"(acc[m]) : "v"(wv2), "v"(ov));
        }
      }
      const float scale = sb2[0][o2], bias = sb2[1][o2];
      float m2 = 0.0f;
#pragma unroll
      for (int m = 0; m < NS2; ++m) {
        m2 = fmaxf(m2, fmaf(acc[m].x, scale, bias));
        m2 = fmaxf(m2, fmaf(acc[m].y, scale, bias));
      }
      pm[tid] = m2;
      __syncthreads();
      if (tid < C2) {
        float mm = pm[tid];
#pragma unroll
        for (int g = 1; g < 256 / C2; ++g) mm = fmaxf(mm, pm[tid + g * C2]);
        out[((size_t)b * 192 + CH_OFF + tid) * P + p] = mm;
      }
    }
    __syncthreads();
  }
}

extern "C" void kernel_launch(void* const* d_in, const int* in_sizes, int n_in,
                              void* d_out, int out_size, void* d_ws, size_t ws_size,
                              hipStream_t stream) {
  const float* xyz   = (const float*)d_in[0];
  const float* feats = (const float*)d_in[1];
  const float* w0_0 = (const float*)d_in[2];
  const float* s0_0 = (const float*)d_in[3];
  const float* b0_0 = (const float*)d_in[4];
  const float* w0_1 = (const float*)d_in[5];
  const float* s0_1 = (const float*)d_in[6];
  const float* b0_1 = (const float*)d_in[7];
  const float* w1_0 = (const float*)d_in[8];
  const float* s1_0 = (const float*)d_in[9];
  const float* b1_0 = (const float*)d_in[10];
  const float* w1_1 = (const float*)d_in[11];
  const float* s1_1 = (const float*)d_in[12];
  const float* b1_1 = (const float*)d_in[13];

  float* out      = (float*)d_out;
  float* new_xyz  = out;                      // (B,P,3)
  float* feat_out = out + (size_t)B * P * 3;  // (B,192,P)

  char* w = (char*)d_ws;
  float* ftr = (float*)w; w += (size_t)B * N * 32 * sizeof(float);  // 16 MB
  float* sox = (float*)w; w += (size_t)B * N * sizeof(float);
  float* soy = (float*)w; w += (size_t)B * N * sizeof(float);
  float* soz = (float*)w; w += (size_t)B * N * sizeof(float);
  int* idx0 = (int*)w; w += (size_t)B * P * 16 * sizeof(int);
  int* idx1 = (int*)w; w += (size_t)B * P * 32 * sizeof(int);

  fps_prep_kernel<<<dim3(8 + B * (N / 256)), dim3(1024), 0, stream>>>(
      xyz, feats, new_xyz, ftr, sox, soy, soz);
  ballq_kernel<<<dim3(B * P / 4), dim3(256), 0, stream>>>(
      sox, soy, soz, new_xyz, idx0, idx1);
  mlp_kernel<16, 32, 64, 0><<<dim3(B * P / 8), dim3(256), 0, stream>>>(
      xyz, ftr, new_xyz, idx0, w0_0, s0_0, b0_0, w0_1, s0_1, b0_1, feat_out);
  mlp_kernel<32, 64, 128, 64><<<dim3(B * P / 8), dim3(256), 0, stream>>>(
      xyz, ftr, new_xyz, idx1, w1_0, s1_0, b1_0, w1_1, s1_1, b1_1, feat_out);
}